// Round 2
// baseline (257.143 us; speedup 1.0000x reference)
//
#include <hip/hip_runtime.h>
#include <hip/hip_bf16.h>

// Swin shifted-window attention, fused. B=64, H=W=56, DIM=128, 4 heads, WS=7.
// fp32 global I/O; bf16 MFMA internally. 1 block = 1 window (4096), wave = head.

#define NTOK 49
#define SCALE 0.08838834764831844f  // 128^-0.5

typedef __bf16 bf16x8 __attribute__((ext_vector_type(8)));
typedef float  f32x4  __attribute__((ext_vector_type(4)));

__device__ __forceinline__ f32x4 mfma_bf16(bf16x8 a, bf16x8 b, f32x4 c) {
  return __builtin_amdgcn_mfma_f32_16x16x32_bf16(a, b, c, 0, 0, 0);
}

__device__ __forceinline__ ushort f2bf(float f) {
  __bf16 h = (__bf16)f;
  return __builtin_bit_cast(ushort, h);
}

__device__ __forceinline__ bf16x8 cvt8(f32x4 a, f32x4 b) {
  bf16x8 r;
#pragma unroll
  for (int j = 0; j < 4; ++j) { r[j] = (__bf16)a[j]; r[4 + j] = (__bf16)b[j]; }
  return r;
}

// region id for the shifted-window mask, computed from window coords.
__device__ __forceinline__ int regid(int t, int wh, int ww) {
  int i = t / 7;
  int j = t - i * 7;
  int rh = (wh == 7) ? ((i < 4) ? 1 : 2) : 0;
  int rw = (ww == 7) ? ((j < 4) ? 1 : 2) : 0;
  return rh * 3 + rw;
}

// Repack a [K x NCOL] row-major fp32 weight into bf16 MFMA B-fragment order:
// packed[((ctg*4 + kt)*64 + lane)*8 + j] = bf16(w[(kt*32 + (lane>>4)*8 + j)*NCOL + ctg*16 + (lane&15)])
__global__ void repack_w(const float* __restrict__ w, ushort* __restrict__ packed, int ncol) {
  int ctg  = blockIdx.x;
  int kt   = threadIdx.x >> 6;
  int lane = threadIdx.x & 63;
  int col  = ctg * 16 + (lane & 15);
  int k0   = kt * 32 + (lane >> 4) * 8;
  ushort* dst = packed + (size_t)((ctg * 4 + kt) * 64 + lane) * 8;
#pragma unroll
  for (int j = 0; j < 8; ++j) dst[j] = f2bf(w[(size_t)(k0 + j) * ncol + col]);
}

__global__ __launch_bounds__(256, 2)
void swin_fused(const float* __restrict__ x,
                const float* __restrict__ qkv_b,
                const float* __restrict__ proj_b,
                const ushort* __restrict__ pqkv,
                const ushort* __restrict__ pproj,
                float* __restrict__ out)
{
  // per-head region (7424 shorts): q[64][40] | k[64][40] | v_t[32][72]; P[64][72] overlays q+k.
  // attnout [64][136] overlays from 0 after a barrier. Total 59392 B.
  __shared__ alignas(16) ushort lds[29696];

  const int wid = blockIdx.x;
  const int b   = wid >> 6;
  const int wh  = (wid >> 3) & 7;
  const int ww  = wid & 7;
  const int tid  = threadIdx.x;
  const int wave = tid >> 6;   // = head
  const int lane = tid & 63;
  const int lrow = lane & 15;
  const int lgrp = lane >> 4;

  ushort* const qb = lds + wave * 7424;
  ushort* const kb = qb + 2560;
  ushort* const vb = qb + 5120;
  ushort* const pb = qb;

  const f32x4 zf = {0.f, 0.f, 0.f, 0.f};

  // ---- Phase 1: xw A-fragments from global (roll applied; rows>=49 zeroed) ----
  bf16x8 a[4][4];
#pragma unroll
  for (int rt = 0; rt < 4; ++rt) {
    int token = rt * 16 + lrow;
    bool valid = token < NTOK;
    int tc = valid ? token : 0;
    int i = tc / 7;
    int j = tc - i * 7;
    int gh = wh * 7 + i + 3; if (gh >= 56) gh -= 56;
    int gw = ww * 7 + j + 3; if (gw >= 56) gw -= 56;
    const float* src = x + (((size_t)((b * 56 + gh) * 56 + gw)) << 7) + lgrp * 8;
#pragma unroll
    for (int kt = 0; kt < 4; ++kt) {
      f32x4 lo = *reinterpret_cast<const f32x4*>(src + kt * 32);
      f32x4 hi = *reinterpret_cast<const f32x4*>(src + kt * 32 + 4);
      bf16x8 v = cvt8(lo, hi);
      a[rt][kt] = valid ? v : bf16x8{};
    }
  }

  // ---- Phase 2: QKV GEMM (wave computes its head's 96 columns) ----
#pragma unroll
  for (int o = 0; o < 3; ++o) {     // 0=q 1=k 2=v
    bf16x8 bw[2][4];
#pragma unroll
    for (int ct = 0; ct < 2; ++ct) {
      int ctg = o * 8 + wave * 2 + ct;
#pragma unroll
      for (int kt = 0; kt < 4; ++kt)
        bw[ct][kt] = *reinterpret_cast<const bf16x8*>(pqkv + (size_t)((ctg * 4 + kt) * 64 + lane) * 8);
    }
    f32x4 acc[4][2];
#pragma unroll
    for (int rt = 0; rt < 4; ++rt)
#pragma unroll
      for (int ct = 0; ct < 2; ++ct) {
        acc[rt][ct] = zf;
#pragma unroll
        for (int kt = 0; kt < 4; ++kt)
          acc[rt][ct] = mfma_bf16(a[rt][kt], bw[ct][kt], acc[rt][ct]);
      }
#pragma unroll
    for (int ct = 0; ct < 2; ++ct) {
      float bias = qkv_b[o * 128 + wave * 32 + ct * 16 + lrow];
#pragma unroll
      for (int rt = 0; rt < 4; ++rt)
#pragma unroll
        for (int r = 0; r < 4; ++r)
          acc[rt][ct][r] += bias;
    }
    if (o == 2) {                   // v transposed: v_t[hd][token], stride 72
#pragma unroll
      for (int rt = 0; rt < 4; ++rt)
#pragma unroll
        for (int ct = 0; ct < 2; ++ct)
#pragma unroll
          for (int r = 0; r < 4; ++r) {
            int token = rt * 16 + lgrp * 4 + r;
            vb[(ct * 16 + lrow) * 72 + token] = f2bf(acc[rt][ct][r]);
          }
    } else {                        // q/k: [token][hd], stride 40
      ushort* dst = (o == 0) ? qb : kb;
#pragma unroll
      for (int rt = 0; rt < 4; ++rt)
#pragma unroll
        for (int ct = 0; ct < 2; ++ct)
#pragma unroll
          for (int r = 0; r < 4; ++r) {
            int token = rt * 16 + lgrp * 4 + r;
            dst[token * 40 + ct * 16 + lrow] = f2bf(acc[rt][ct][r]);
          }
    }
  }

  // ---- Phase 3: S = q k^T, mask, softmax (per wave = per head) ----
  bf16x8 aq[4], bk[4];
#pragma unroll
  for (int rt = 0; rt < 4; ++rt)
    aq[rt] = *reinterpret_cast<const bf16x8*>(qb + (rt * 16 + lrow) * 40 + lgrp * 8);
#pragma unroll
  for (int ct = 0; ct < 4; ++ct)
    bk[ct] = *reinterpret_cast<const bf16x8*>(kb + (ct * 16 + lrow) * 40 + lgrp * 8);

  f32x4 s[4][4];
#pragma unroll
  for (int rt = 0; rt < 4; ++rt)
#pragma unroll
    for (int ct = 0; ct < 4; ++ct)
      s[rt][ct] = mfma_bf16(aq[rt], bk[ct], zf);

  int cid[4]; bool cok[4];
#pragma unroll
  for (int ct = 0; ct < 4; ++ct) {
    int tc = ct * 16 + lrow;
    cok[ct] = tc < NTOK;
    cid[ct] = regid(tc, wh, ww);
  }

  float rinv[4][4];
#pragma unroll
  for (int rt = 0; rt < 4; ++rt) {
#pragma unroll
    for (int r = 0; r < 4; ++r) {
      int tr = rt * 16 + lgrp * 4 + r;
      int rid = regid(tr, wh, ww);
      float m = -3e38f;
#pragma unroll
      for (int ct = 0; ct < 4; ++ct) {
        float v = s[rt][ct][r] * SCALE;
        if (!cok[ct] || cid[ct] != rid) v = -1e9f;
        s[rt][ct][r] = v;
        m = fmaxf(m, v);
      }
      m = fmaxf(m, __shfl_xor(m, 1));
      m = fmaxf(m, __shfl_xor(m, 2));
      m = fmaxf(m, __shfl_xor(m, 4));
      m = fmaxf(m, __shfl_xor(m, 8));
      float sum = 0.f;
#pragma unroll
      for (int ct = 0; ct < 4; ++ct) {
        float e = __expf(s[rt][ct][r] - m);
        s[rt][ct][r] = e;
        sum += e;
      }
      sum += __shfl_xor(sum, 1);
      sum += __shfl_xor(sum, 2);
      sum += __shfl_xor(sum, 4);
      sum += __shfl_xor(sum, 8);
      rinv[rt][r] = 1.f / sum;
#pragma unroll
      for (int ct = 0; ct < 4; ++ct)   // P (unnormalized) -> LDS, stride 72
        pb[tr * 72 + ct * 16 + lrow] = f2bf(s[rt][ct][r]);
    }
  }

  // ---- PV: out_h = P @ v  (K = 64 keys) ----
  bf16x8 ap[4][2], bv[2][2];
#pragma unroll
  for (int rt = 0; rt < 4; ++rt)
#pragma unroll
    for (int kt = 0; kt < 2; ++kt)
      ap[rt][kt] = *reinterpret_cast<const bf16x8*>(pb + (rt * 16 + lrow) * 72 + kt * 32 + lgrp * 8);
#pragma unroll
  for (int kt = 0; kt < 2; ++kt)
#pragma unroll
    for (int ct = 0; ct < 2; ++ct)
      bv[kt][ct] = *reinterpret_cast<const bf16x8*>(vb + (ct * 16 + lrow) * 72 + kt * 32 + lgrp * 8);

  f32x4 pv[4][2];
#pragma unroll
  for (int rt = 0; rt < 4; ++rt)
#pragma unroll
    for (int ct = 0; ct < 2; ++ct) {
      pv[rt][ct] = zf;
#pragma unroll
      for (int kt = 0; kt < 2; ++kt)
        pv[rt][ct] = mfma_bf16(ap[rt][kt], bv[kt][ct], pv[rt][ct]);
    }

  __syncthreads();   // all waves done reading their P/v; reuse LDS for attnout

  ushort* const ao = lds;   // [64][136]
#pragma unroll
  for (int rt = 0; rt < 4; ++rt)
#pragma unroll
    for (int ct = 0; ct < 2; ++ct)
#pragma unroll
      for (int r = 0; r < 4; ++r) {
        int token = rt * 16 + lgrp * 4 + r;
        ao[token * 136 + wave * 32 + ct * 16 + lrow] = f2bf(pv[rt][ct][r] * rinv[rt][r]);
      }
  __syncthreads();

  // ---- Phase 4: proj GEMM (wave computes cols [wave*32, wave*32+32)) ----
  f32x4 acc2[4][2];
#pragma unroll
  for (int rt = 0; rt < 4; ++rt)
#pragma unroll
    for (int ct = 0; ct < 2; ++ct)
      acc2[rt][ct] = zf;
#pragma unroll
  for (int kt = 0; kt < 4; ++kt) {
    bf16x8 a2[4], b2[2];
#pragma unroll
    for (int rt = 0; rt < 4; ++rt)
      a2[rt] = *reinterpret_cast<const bf16x8*>(ao + (rt * 16 + lrow) * 136 + kt * 32 + lgrp * 8);
#pragma unroll
    for (int ct = 0; ct < 2; ++ct) {
      int ctg = wave * 2 + ct;
      b2[ct] = *reinterpret_cast<const bf16x8*>(pproj + (size_t)((ctg * 4 + kt) * 64 + lane) * 8);
    }
#pragma unroll
    for (int rt = 0; rt < 4; ++rt)
#pragma unroll
      for (int ct = 0; ct < 2; ++ct)
        acc2[rt][ct] = mfma_bf16(a2[rt], b2[ct], acc2[rt][ct]);
  }

  float bias2[2];
#pragma unroll
  for (int ct = 0; ct < 2; ++ct)
    bias2[ct] = proj_b[wave * 32 + ct * 16 + lrow];

  // ---- Epilogue: reverse roll, store fp32 ----
#pragma unroll
  for (int rt = 0; rt < 4; ++rt)
#pragma unroll
    for (int r = 0; r < 4; ++r) {
      int token = rt * 16 + lgrp * 4 + r;
      if (token < NTOK) {
        int i = token / 7;
        int j = token - i * 7;
        int oh = wh * 7 + i + 3; if (oh >= 56) oh -= 56;
        int ow = ww * 7 + j + 3; if (ow >= 56) ow -= 56;
        float* dst = out + (((size_t)((b * 56 + oh) * 56 + ow)) << 7) + wave * 32;
#pragma unroll
        for (int ct = 0; ct < 2; ++ct)
          dst[ct * 16 + lrow] = acc2[rt][ct][r] + bias2[ct];
      }
    }
}

extern "C" void kernel_launch(void* const* d_in, const int* in_sizes, int n_in,
                              void* d_out, int out_size, void* d_ws, size_t ws_size,
                              hipStream_t stream) {
  const float* x      = (const float*)d_in[0];
  const float* qkv_w  = (const float*)d_in[1];
  const float* qkv_b  = (const float*)d_in[2];
  const float* proj_w = (const float*)d_in[3];
  const float* proj_b = (const float*)d_in[4];
  float* out = (float*)d_out;

  ushort* pqkv  = (ushort*)d_ws;            // 24*4*64*8 = 49152 shorts (96 KiB)
  ushort* pproj = pqkv + 49152;             //  8*4*64*8 = 16384 shorts (32 KiB)

  repack_w<<<24, 256, 0, stream>>>(qkv_w, pqkv, 384);
  repack_w<<<8, 256, 0, stream>>>(proj_w, pproj, 128);
  swin_fused<<<4096, 256, 0, stream>>>(x, qkv_b, proj_b, pqkv, pproj, out);
}